// Round 3
// baseline (672.248 us; speedup 1.0000x reference)
//
#include <hip/hip_runtime.h>

#define PGD   10
#define ALPHA 0.15f
#define NTAB  32
#define SPT   8
#define NTHR  256

// ws float layout:
//   [0,    320)    counts_tab[NTAB][10]
//   [320,  32320)  S_tab[PGD][NTAB][100]
//   [32320,33320)  D_glob[10][100]  (slot s = cumulative D after s+1 steps; 0..8 used)
#define WS_COUNTS 0
#define WS_STAB   320
#define WS_DGLOB  32320
#define WS_ZERO_N 33320

__global__ void k_init(float* __restrict__ ws, float* __restrict__ out) {
    int i = blockIdx.x * blockDim.x + threadIdx.x;
    if (i == 0) out[0] = 0.f;
    int gs = gridDim.x * blockDim.x;
    for (int k = i; k < WS_ZERO_N; k += gs) ws[k] = 0.f;
}

__global__ __launch_bounds__(NTHR, 2) void k_step(
    const float* __restrict__ logit, const int* __restrict__ y,
    float* __restrict__ ws, int B, int t /*1..10*/)
{
    __shared__ float tab[100][NTAB];   // lane-dedicated banks: tab[cj][lane&31]
    __shared__ float ctab[10][NTAB];
    __shared__ float sh_D[100];
    __shared__ float shT[100];
    __shared__ float shCnt[10];
    __shared__ float shCn[10];

    const int tid = threadIdx.x;
    const int gth = gridDim.x * NTHR;
    const int base = blockIdx.x * NTHR + tid;

    float* counts_tab = ws + WS_COUNTS;
    float* S_tab      = ws + WS_STAB;
    float* D_glob     = ws + WS_DGLOB;

    // ---- issue all sample loads FIRST (48 independent loads in flight) ----
    float xv[SPT][10];
    int   yc[SPT];
    #pragma unroll
    for (int k = 0; k < SPT; ++k) {
        int idx = base + k * gth;
        if (idx < B) {
            yc[k] = y[idx];
            const float2* rp = reinterpret_cast<const float2*>(logit + (size_t)idx * 10);
            #pragma unroll
            for (int q = 0; q < 5; ++q) {
                float2 v = rp[q];
                xv[k][2 * q] = v.x; xv[k][2 * q + 1] = v.y;
            }
        } else {
            yc[k] = -1;
            #pragma unroll
            for (int j = 0; j < 10; ++j) xv[k][j] = 0.f;
        }
    }

    // ---- zero LDS tables ----
    for (int i = tid; i < 100 * NTAB; i += NTHR) (&tab[0][0])[i] = 0.f;
    if (t == 1) for (int i = tid; i < 10 * NTAB; i += NTHR) (&ctab[0][0])[i] = 0.f;

    // ---- table phase (t>=2): recompute D_{t-1}, identical in every block ----
    if (t >= 2) {
        const float* Sg = S_tab + (size_t)(t - 2) * (NTAB * 100);
        if (tid < 10) {
            float s = 0.f;
            #pragma unroll
            for (int k = 0; k < NTAB; ++k) s += counts_tab[k * 10 + tid];
            shCnt[tid] = (s == 0.f) ? 100.f : s;
        }
        if (tid < 100) {
            float s = 0.f;
            #pragma unroll
            for (int k = 0; k < NTAB; ++k) s += Sg[k * 100 + tid];
            shT[tid] = s;
        }
        __syncthreads();
        if (tid < 100) {
            int c = tid / 10, j = tid - c * 10;
            shT[tid] = shT[tid] / shCnt[c] - ((c == j) ? 1.f : 0.f);
        }
        __syncthreads();
        if (tid < 10) {  // column norms (torch-faithful: row c divided by col_norm[c])
            float s = 0.f;
            for (int cc = 0; cc < 10; ++cc) { float g = shT[cc * 10 + tid]; s += g * g; }
            shCn[tid] = sqrtf(s);
        }
        __syncthreads();
        if (tid < 100) {
            int c = tid / 10;
            float sign = (c < 4) ? -1.f : 1.f;   // SIGN_VEC = [-1]*4 + [1]*6
            float g = shT[tid] / shCn[c] * (ALPHA * sign);
            sh_D[tid] = ((t >= 3) ? D_glob[(size_t)(t - 3) * 100 + tid] : 0.f) + g;
        }
        __syncthreads();
        if (blockIdx.x == 0 && tid < 100) D_glob[(size_t)(t - 2) * 100 + tid] = sh_D[tid];
    }
    __syncthreads();   // tables zeroed + sh_D ready

    // ---- sample phase: softmax + conflict-free LDS scatter ----
    const int lane31 = tid & 31;
    #pragma unroll
    for (int k = 0; k < SPT; ++k) {
        int c = yc[k];
        if (c < 0) continue;
        float tv[10];
        #pragma unroll
        for (int j = 0; j < 10; ++j) tv[j] = xv[k][j];
        if (t >= 2) {
            #pragma unroll
            for (int j = 0; j < 10; ++j) tv[j] += sh_D[c * 10 + j];
        }
        float m = tv[0];
        #pragma unroll
        for (int j = 1; j < 10; ++j) m = fmaxf(m, tv[j]);
        float s = 0.f;
        #pragma unroll
        for (int j = 0; j < 10; ++j) { tv[j] = __expf(tv[j] - m); s += tv[j]; }
        float r = 1.f / s;
        #pragma unroll
        for (int j = 0; j < 10; ++j) unsafeAtomicAdd(&tab[c * 10 + j][lane31], tv[j] * r);
        if (t == 1) unsafeAtomicAdd(&ctab[c][lane31], 1.f);
    }
    __syncthreads();

    // ---- flush block partials to spread global tables ----
    const int tb = blockIdx.x & (NTAB - 1);
    if (tid < 100) {
        float s = 0.f;
        #pragma unroll
        for (int k = 0; k < NTAB; ++k) s += tab[tid][(tid + k) & (NTAB - 1)];
        unsafeAtomicAdd(&S_tab[(size_t)(t - 1) * (NTAB * 100) + (size_t)tb * 100 + tid], s);
    }
    if (t == 1 && tid < 10) {
        float s = 0.f;
        #pragma unroll
        for (int k = 0; k < NTAB; ++k) s += ctab[tid][(tid + k) & (NTAB - 1)];
        unsafeAtomicAdd(&counts_tab[tb * 10 + tid], s);
    }
}

__global__ __launch_bounds__(NTHR, 2) void k_final(
    const float* __restrict__ logit, const int* __restrict__ y,
    const int* __restrict__ label_freq,
    float* __restrict__ out, float* __restrict__ ws, int B)
{
    __shared__ float Dall[PGD][100];
    __shared__ float shT[100];
    __shared__ float shCnt[10];
    __shared__ float shCn[10];
    __shared__ int   lf[10];
    __shared__ float wsum[4];

    const int tid = threadIdx.x;
    const int gth = gridDim.x * NTHR;
    const int base = blockIdx.x * NTHR + tid;

    float* counts_tab = ws + WS_COUNTS;
    float* S_tab      = ws + WS_STAB;
    float* D_glob     = ws + WS_DGLOB;

    // ---- issue sample loads first ----
    float xv[SPT][10];
    int   yc[SPT];
    #pragma unroll
    for (int k = 0; k < SPT; ++k) {
        int idx = base + k * gth;
        if (idx < B) {
            yc[k] = y[idx];
            const float2* rp = reinterpret_cast<const float2*>(logit + (size_t)idx * 10);
            #pragma unroll
            for (int q = 0; q < 5; ++q) {
                float2 v = rp[q];
                xv[k][2 * q] = v.x; xv[k][2 * q + 1] = v.y;
            }
        } else {
            yc[k] = -1;
            #pragma unroll
            for (int j = 0; j < 10; ++j) xv[k][j] = 0.f;
        }
    }

    // ---- D_10 from S_tab[9] + D_glob[8]; load D_glob[0..8] ----
    {
        const float* Sg = S_tab + (size_t)9 * (NTAB * 100);
        if (tid < 10) {
            float s = 0.f;
            #pragma unroll
            for (int k = 0; k < NTAB; ++k) s += counts_tab[k * 10 + tid];
            shCnt[tid] = (s == 0.f) ? 100.f : s;
        }
        if (tid < 100) {
            float s = 0.f;
            #pragma unroll
            for (int k = 0; k < NTAB; ++k) s += Sg[k * 100 + tid];
            shT[tid] = s;
        }
        __syncthreads();
        if (tid < 100) {
            int c = tid / 10, j = tid - c * 10;
            shT[tid] = shT[tid] / shCnt[c] - ((c == j) ? 1.f : 0.f);
        }
        __syncthreads();
        if (tid < 10) {
            float s = 0.f;
            for (int cc = 0; cc < 10; ++cc) { float g = shT[cc * 10 + tid]; s += g * g; }
            shCn[tid] = sqrtf(s);
        }
        __syncthreads();
        if (tid < 100) {
            int c = tid / 10;
            float sign = (c < 4) ? -1.f : 1.f;
            float g = shT[tid] / shCn[c] * (ALPHA * sign);
            Dall[9][tid] = D_glob[8 * 100 + tid] + g;
        }
        for (int i = tid; i < 900; i += NTHR) Dall[i / 100][i % 100] = D_glob[i];
        if (tid < 10) lf[tid] = label_freq[tid];
        __syncthreads();
    }

    // ---- outputs + CE ----
    float* news_out = out + 1;
    float* copy_out = out + 1 + (size_t)B * 10;
    float acc = 0.f;
    #pragma unroll
    for (int k = 0; k < SPT; ++k) {
        int idx = base + k * gth;
        if (idx >= B) continue;
        int c = yc[k];
        int sel = lf[c];                       // state after sel+1 steps == Dall[sel]
        float nv[10];
        #pragma unroll
        for (int j = 0; j < 10; ++j) nv[j] = xv[k][j] + Dall[sel][c * 10 + j];
        float2* np = reinterpret_cast<float2*>(news_out + (size_t)idx * 10);
        float2* cp = reinterpret_cast<float2*>(copy_out + (size_t)idx * 10);
        #pragma unroll
        for (int q = 0; q < 5; ++q) {
            np[q] = make_float2(nv[2 * q], nv[2 * q + 1]);
            cp[q] = make_float2(xv[k][2 * q], xv[k][2 * q + 1]);
        }
        float m = nv[0];
        #pragma unroll
        for (int j = 1; j < 10; ++j) m = fmaxf(m, nv[j]);
        float s = 0.f;
        #pragma unroll
        for (int j = 0; j < 10; ++j) s += __expf(nv[j] - m);
        acc += __logf(s) + m - nv[c];
    }
    #pragma unroll
    for (int off = 32; off > 0; off >>= 1) acc += __shfl_down(acc, off);
    if ((tid & 63) == 0) wsum[tid >> 6] = acc;
    __syncthreads();
    if (tid == 0)
        unsafeAtomicAdd(out, (wsum[0] + wsum[1] + wsum[2] + wsum[3]) / (float)B);
}

extern "C" void kernel_launch(void* const* d_in, const int* in_sizes, int n_in,
                              void* d_out, int out_size, void* d_ws, size_t ws_size,
                              hipStream_t stream) {
    const float* logit = (const float*)d_in[0];
    const int*   yy    = (const int*)d_in[1];
    const int*   lf    = (const int*)d_in[2];
    float* out = (float*)d_out;
    float* ws  = (float*)d_ws;
    int B = in_sizes[0] / 10;

    int blocks = (B + NTHR * SPT - 1) / (NTHR * SPT);   // 512 for B = 1M

    hipLaunchKernelGGL(k_init, dim3(64), dim3(NTHR), 0, stream, ws, out);
    for (int t = 1; t <= PGD; ++t)
        hipLaunchKernelGGL(k_step, dim3(blocks), dim3(NTHR), 0, stream,
                           logit, yy, ws, B, t);
    hipLaunchKernelGGL(k_final, dim3(blocks), dim3(NTHR), 0, stream,
                       logit, yy, lf, out, ws, B);
}

// Round 6
// 566.585 us; speedup vs baseline: 1.1865x; 1.1865x over previous
//
#include <hip/hip_runtime.h>

#define PGD   10
#define ALPHA 0.15f
#define NTAB  32
#define NTHR  256
#define SPT   4
#define FTHR  256
#define FSPT  4

// ws float layout (identical to rounds 1/3):
//   [0,    320)    counts_tab[NTAB][10]
//   [320,  32320)  S_tab[PGD][NTAB][100]
//   [32320,33320)  D_glob[10][100]  (slot s = cumulative D after s+1 steps; 0..8 used)
#define WS_COUNTS 0
#define WS_STAB   320
#define WS_DGLOB  32320
#define WS_ZERO_N 33320

__global__ void k_init(float* __restrict__ ws, float* __restrict__ out) {
    int i = blockIdx.x * blockDim.x + threadIdx.x;
    if (i == 0) out[0] = 0.f;
    int gs = gridDim.x * blockDim.x;
    for (int k = i; k < WS_ZERO_N; k += gs) ws[k] = 0.f;
}

__global__ __launch_bounds__(NTHR) void k_step(
    const float* __restrict__ logit, const int* __restrict__ y,
    float* __restrict__ ws, int B, int t /*1..10*/)
{
    __shared__ float sh_D[100];
    __shared__ float shT[100];
    __shared__ float shCnt[10];
    __shared__ float shCn[10];
    __shared__ float wtab[110][5];   // [row][wave] block partials (pad to 5)

    const int tid = threadIdx.x;
    const int gth = gridDim.x * NTHR;
    const int base = blockIdx.x * NTHR + tid;

    float* counts_tab = ws + WS_COUNTS;
    float* S_tab      = ws + WS_STAB;
    float* D_glob     = ws + WS_DGLOB;

    // ---- table phase (t>=2): recompute D_{t-1}, EXACT round-3 fp32 code ----
    if (t >= 2) {
        const float* Sg = S_tab + (size_t)(t - 2) * (NTAB * 100);
        if (tid < 10) {
            float s = 0.f;
            #pragma unroll
            for (int k = 0; k < NTAB; ++k) s += counts_tab[k * 10 + tid];
            shCnt[tid] = (s == 0.f) ? 100.f : s;
        }
        if (tid < 100) {
            float s = 0.f;
            #pragma unroll
            for (int k = 0; k < NTAB; ++k) s += Sg[k * 100 + tid];
            shT[tid] = s;
        }
        __syncthreads();
        if (tid < 100) {
            int c = tid / 10, j = tid - c * 10;
            shT[tid] = shT[tid] / shCnt[c] - ((c == j) ? 1.f : 0.f);
        }
        __syncthreads();
        if (tid < 10) {  // column norms (torch-faithful: row c divided by col_norm[c])
            float s = 0.f;
            for (int cc = 0; cc < 10; ++cc) { float g = shT[cc * 10 + tid]; s += g * g; }
            shCn[tid] = sqrtf(s);
        }
        __syncthreads();
        if (tid < 100) {
            int c = tid / 10;
            float sign = (c < 4) ? -1.f : 1.f;   // SIGN_VEC = [-1]*4 + [1]*6
            float g = shT[tid] / shCn[c] * (ALPHA * sign);
            sh_D[tid] = ((t >= 3) ? D_glob[(size_t)(t - 3) * 100 + tid] : 0.f) + g;
        }
        __syncthreads();
        if (blockIdx.x == 0 && tid < 100) D_glob[(size_t)(t - 2) * 100 + tid] = sh_D[tid];
    }
    __syncthreads();

    // ---- sample phase: softmax + REGISTER binning (no LDS atomics) ----
    float racc[100];
    float rcnt[10];
    #pragma unroll
    for (int i = 0; i < 100; ++i) racc[i] = 0.f;
    #pragma unroll
    for (int i = 0; i < 10; ++i) rcnt[i] = 0.f;

    #pragma unroll
    for (int k = 0; k < SPT; ++k) {
        int idx = base + k * gth;
        if (idx >= B) break;
        int c = y[idx];
        const float2* rp = reinterpret_cast<const float2*>(logit + (size_t)idx * 10);
        float tv[10];
        #pragma unroll
        for (int q = 0; q < 5; ++q) {
            float2 v = rp[q];
            tv[2 * q] = v.x; tv[2 * q + 1] = v.y;
        }
        if (t >= 2) {
            #pragma unroll
            for (int j = 0; j < 10; ++j) tv[j] += sh_D[c * 10 + j];
        }
        float m = tv[0];
        #pragma unroll
        for (int j = 1; j < 10; ++j) m = fmaxf(m, tv[j]);
        float s = 0.f;
        #pragma unroll
        for (int j = 0; j < 10; ++j) { tv[j] = __expf(tv[j] - m); s += tv[j]; }
        float r = 1.f / s;
        #pragma unroll
        for (int j = 0; j < 10; ++j) tv[j] *= r;
        // bin into the class row (exec-masked, all indices compile-time)
        #pragma unroll
        for (int cc = 0; cc < 10; ++cc) {
            if (c == cc) {
                #pragma unroll
                for (int j = 0; j < 10; ++j) racc[cc * 10 + j] += tv[j];
                rcnt[cc] += 1.f;
            }
        }
    }

    // ---- flush: 64-lane butterfly per row -> wave partials -> global atomics ----
    const int wave = tid >> 6;
    const bool lane0 = (tid & 63) == 0;
    #pragma unroll
    for (int r0 = 0; r0 < 100; ++r0) {
        float v = racc[r0];
        v += __shfl_xor(v, 1);
        v += __shfl_xor(v, 2);
        v += __shfl_xor(v, 4);
        v += __shfl_xor(v, 8);
        v += __shfl_xor(v, 16);
        v += __shfl_xor(v, 32);
        if (lane0) wtab[r0][wave] = v;
    }
    if (t == 1) {
        #pragma unroll
        for (int r0 = 0; r0 < 10; ++r0) {
            float v = rcnt[r0];
            v += __shfl_xor(v, 1);
            v += __shfl_xor(v, 2);
            v += __shfl_xor(v, 4);
            v += __shfl_xor(v, 8);
            v += __shfl_xor(v, 16);
            v += __shfl_xor(v, 32);
            if (lane0) wtab[100 + r0][wave] = v;
        }
    }
    __syncthreads();

    const int tb = blockIdx.x & (NTAB - 1);
    if (tid < 100) {
        float s = wtab[tid][0] + wtab[tid][1] + wtab[tid][2] + wtab[tid][3];
        unsafeAtomicAdd(&S_tab[(size_t)(t - 1) * (NTAB * 100) + (size_t)tb * 100 + tid], s);
    }
    if (t == 1 && tid < 10) {
        float s = wtab[100 + tid][0] + wtab[100 + tid][1] + wtab[100 + tid][2] + wtab[100 + tid][3];
        unsafeAtomicAdd(&counts_tab[tb * 10 + tid], s);
    }
}

__global__ __launch_bounds__(FTHR, 2) void k_final(
    const float* __restrict__ logit, const int* __restrict__ y,
    const int* __restrict__ label_freq,
    float* __restrict__ out, float* __restrict__ ws, int B)
{
    __shared__ float Dall[PGD][100];
    __shared__ float shT[100];
    __shared__ float shCnt[10];
    __shared__ float shCn[10];
    __shared__ int   lf[10];
    __shared__ float wsum[4];

    const int tid = threadIdx.x;
    const int gth = gridDim.x * FTHR;
    const int base = blockIdx.x * FTHR + tid;

    float* counts_tab = ws + WS_COUNTS;
    float* S_tab      = ws + WS_STAB;
    float* D_glob     = ws + WS_DGLOB;

    // ---- issue sample loads first ----
    float xv[FSPT][10];
    int   yc[FSPT];
    #pragma unroll
    for (int k = 0; k < FSPT; ++k) {
        int idx = base + k * gth;
        if (idx < B) {
            yc[k] = y[idx];
            const float2* rp = reinterpret_cast<const float2*>(logit + (size_t)idx * 10);
            #pragma unroll
            for (int q = 0; q < 5; ++q) {
                float2 v = rp[q];
                xv[k][2 * q] = v.x; xv[k][2 * q + 1] = v.y;
            }
        } else {
            yc[k] = -1;
            #pragma unroll
            for (int j = 0; j < 10; ++j) xv[k][j] = 0.f;
        }
    }

    // ---- D_10 from S_tab[9] + D_glob[8]; load D_glob[0..8] (round-3 code) ----
    {
        const float* Sg = S_tab + (size_t)9 * (NTAB * 100);
        if (tid < 10) {
            float s = 0.f;
            #pragma unroll
            for (int k = 0; k < NTAB; ++k) s += counts_tab[k * 10 + tid];
            shCnt[tid] = (s == 0.f) ? 100.f : s;
        }
        if (tid < 100) {
            float s = 0.f;
            #pragma unroll
            for (int k = 0; k < NTAB; ++k) s += Sg[k * 100 + tid];
            shT[tid] = s;
        }
        __syncthreads();
        if (tid < 100) {
            int c = tid / 10, j = tid - c * 10;
            shT[tid] = shT[tid] / shCnt[c] - ((c == j) ? 1.f : 0.f);
        }
        __syncthreads();
        if (tid < 10) {
            float s = 0.f;
            for (int cc = 0; cc < 10; ++cc) { float g = shT[cc * 10 + tid]; s += g * g; }
            shCn[tid] = sqrtf(s);
        }
        __syncthreads();
        if (tid < 100) {
            int c = tid / 10;
            float sign = (c < 4) ? -1.f : 1.f;
            float g = shT[tid] / shCn[c] * (ALPHA * sign);
            Dall[9][tid] = D_glob[8 * 100 + tid] + g;
        }
        for (int i = tid; i < 900; i += FTHR) Dall[i / 100][i % 100] = D_glob[i];
        if (tid < 10) lf[tid] = label_freq[tid];
        __syncthreads();
    }

    // ---- outputs + CE ----
    float* news_out = out + 1;
    float* copy_out = out + 1 + (size_t)B * 10;
    float acc = 0.f;
    #pragma unroll
    for (int k = 0; k < FSPT; ++k) {
        int idx = base + k * gth;
        if (idx >= B) continue;
        int c = yc[k];
        int sel = lf[c];                       // state after sel+1 steps == Dall[sel]
        float nv[10];
        #pragma unroll
        for (int j = 0; j < 10; ++j) nv[j] = xv[k][j] + Dall[sel][c * 10 + j];
        float2* np = reinterpret_cast<float2*>(news_out + (size_t)idx * 10);
        float2* cp = reinterpret_cast<float2*>(copy_out + (size_t)idx * 10);
        #pragma unroll
        for (int q = 0; q < 5; ++q) {
            np[q] = make_float2(nv[2 * q], nv[2 * q + 1]);
            cp[q] = make_float2(xv[k][2 * q], xv[k][2 * q + 1]);
        }
        float m = nv[0];
        #pragma unroll
        for (int j = 1; j < 10; ++j) m = fmaxf(m, nv[j]);
        float s = 0.f;
        #pragma unroll
        for (int j = 0; j < 10; ++j) s += __expf(nv[j] - m);
        acc += __logf(s) + m - nv[c];
    }
    #pragma unroll
    for (int off = 32; off > 0; off >>= 1) acc += __shfl_down(acc, off);
    if ((tid & 63) == 0) wsum[tid >> 6] = acc;
    __syncthreads();
    if (tid == 0)
        unsafeAtomicAdd(out, (wsum[0] + wsum[1] + wsum[2] + wsum[3]) / (float)B);
}

extern "C" void kernel_launch(void* const* d_in, const int* in_sizes, int n_in,
                              void* d_out, int out_size, void* d_ws, size_t ws_size,
                              hipStream_t stream) {
    const float* logit = (const float*)d_in[0];
    const int*   yy    = (const int*)d_in[1];
    const int*   lf    = (const int*)d_in[2];
    float* out = (float*)d_out;
    float* ws  = (float*)d_ws;
    int B = in_sizes[0] / 10;

    int blocks  = (B + NTHR * SPT - 1) / (NTHR * SPT);    // 1024 for B = 1M
    int fblocks = (B + FTHR * FSPT - 1) / (FTHR * FSPT);  // 1024

    hipLaunchKernelGGL(k_init, dim3(64), dim3(256), 0, stream, ws, out);
    for (int t = 1; t <= PGD; ++t)
        hipLaunchKernelGGL(k_step, dim3(blocks), dim3(NTHR), 0, stream,
                           logit, yy, ws, B, t);
    hipLaunchKernelGGL(k_final, dim3(fblocks), dim3(FTHR), 0, stream,
                       logit, yy, lf, out, ws, B);
}